// Round 1
// baseline (1684.020 us; speedup 1.0000x reference)
//
#include <hip/hip_runtime.h>

// Bidirectional GRU (Keras reset_after) for B=32,T=128,E=512,U=1024.
// Pipeline: embed-cast -> weight transposes -> x_proj GEMM (bf16 MFMA)
//           -> persistent spin-synced recurrent kernel (weights in VGPRs).

using u16 = unsigned short;
using u32 = unsigned int;
typedef __attribute__((ext_vector_type(8))) short bfx8;   // 8 bf16 = 4 VGPR (MFMA A/B frag)
typedef __attribute__((ext_vector_type(4))) float f32x4;  // MFMA C/D frag

#define B_ 32
#define T_ 128
#define E_ 512
#define U_ 1024
#define NG 3072           // 3*U
#define M_ 4096           // B*T
#define YN 4194304        // B*T*U (y elements in d_out)

__device__ __forceinline__ float bf2f(u16 u) {
  union { u32 i; float f; } v; v.i = (u32)u << 16; return v.f;
}
__device__ __forceinline__ u16 f2bf(float f) {
  union { float f; u32 i; } v; v.f = f;
  u32 r = v.i + 0x7FFFu + ((v.i >> 16) & 1u);   // RNE
  return (u16)(r >> 16);
}
__device__ __forceinline__ float sigm(float x) { return 1.0f / (1.0f + __expf(-x)); }

__device__ __forceinline__ void load_lds16(const void* g, void* l) {
  __builtin_amdgcn_global_load_lds(
      (const __attribute__((address_space(1))) u32*)g,
      (__attribute__((address_space(3))) u32*)l, 16, 0, 0);
}

// ---------------- P1: embedding gather + cast to bf16. X[m=t*32+b][k] ----------------
__global__ __launch_bounds__(256) void k_embed(const int* __restrict__ tok,
                                               const float* __restrict__ emb,
                                               u16* __restrict__ X) {
  int idx = blockIdx.x * 256 + threadIdx.x;      // 4096*512/8 = 262144 threads
  int m = idx >> 6, k8 = (idx & 63) << 3;
  int b = m & 31, t = m >> 5;
  int tk = tok[b * T_ + t];
  const float* s = emb + (size_t)tk * E_ + k8;
  float4 v0 = *(const float4*)s, v1 = *(const float4*)(s + 4);
  bfx8 r;
  r[0]=(short)f2bf(v0.x); r[1]=(short)f2bf(v0.y); r[2]=(short)f2bf(v0.z); r[3]=(short)f2bf(v0.w);
  r[4]=(short)f2bf(v1.x); r[5]=(short)f2bf(v1.y); r[6]=(short)f2bf(v1.z); r[7]=(short)f2bf(v1.w);
  *(bfx8*)(X + (size_t)m * E_ + k8) = r;
}

// ------------- P2/P3: transpose [K][N] f32 -> [N][K] bf16 (remap packs GRU slices) -------------
__global__ void k_transpose(const float* __restrict__ in, u16* __restrict__ out,
                            int K, int N, int remap) {
  __shared__ float tile[32][33];
  int k0 = blockIdx.x * 32, n0 = blockIdx.y * 32;
  int tx = threadIdx.x, ty = threadIdx.y;        // block (32,8)
  for (int j = ty; j < 32; j += 8) tile[j][tx] = in[(size_t)(k0 + j) * N + n0 + tx];
  __syncthreads();
  for (int j = ty; j < 32; j += 8) {
    int n = n0 + j;
    // remap: source col n = g*1024+u  ->  row = (u>>5)*96 + g*32 + (u&31)
    int row = remap ? ((((n & 1023) >> 5) * 96) + ((n >> 10) << 5) + (n & 31)) : n;
    out[(size_t)row * K + k0 + tx] = f2bf(tile[tx][j]);
  }
}

// ---------------- G: x_proj GEMM.  XP[dir][m][n] = X[m][:] @ W[:,n] + bias0[n]  (bf16 out) ----------------
__global__ __launch_bounds__(256) void k_xproj(const u16* __restrict__ X,
                                               const u16* __restrict__ WT,   // [2][3072][512]
                                               const float* __restrict__ biasF,
                                               const float* __restrict__ biasB,
                                               u16* __restrict__ XP) {
  const int n0 = blockIdx.x * 128, m0 = blockIdx.y * 128, dir = blockIdx.z;
  const float* bias = dir ? biasB : biasF;             // row 0
  const u16* Wd = WT + (size_t)dir * NG * E_;
  __shared__ __align__(16) u16 As[128 * 64];
  __shared__ __align__(16) u16 Bs[128 * 64];
  const int tid = threadIdx.x;
  const int wave = tid >> 6, lane = tid & 63;
  const int moff = (wave >> 1) * 64, noff = (wave & 1) * 64;
  const int l15 = lane & 15, l4 = lane >> 4;
  f32x4 acc[4][4] = {};
  for (int kt = 0; kt < 8; ++kt) {
    int k0 = kt * 64;
    // stage 16KB A + 16KB B via global_load_lds (linear dest, inverse-swizzled source)
#pragma unroll
    for (int j = 0; j < 4; ++j) {
      int o = j * 4096 + tid * 16;
      int row = o >> 7;
      int kk = (((o & 127) ^ ((row & 7) << 4)) >> 1);
      load_lds16(X  + (size_t)(m0 + row) * E_ + k0 + kk, (char*)As + o);
      load_lds16(Wd + (size_t)(n0 + row) * E_ + k0 + kk, (char*)Bs + o);
    }
    __syncthreads();
#pragma unroll
    for (int Ks = 0; Ks < 2; ++Ks) {
      bfx8 a[4], b[4];
#pragma unroll
      for (int Mt = 0; Mt < 4; ++Mt) {
        int ra = moff + Mt * 16 + l15;
        int ba = (ra << 7) + ((Ks * 32 + l4 * 8) << 1);
        ba ^= (ra & 7) << 4;                      // swizzled read
        a[Mt] = *(const bfx8*)((const char*)As + ba);
      }
#pragma unroll
      for (int Nt = 0; Nt < 4; ++Nt) {
        int rb = noff + Nt * 16 + l15;
        int bb2 = (rb << 7) + ((Ks * 32 + l4 * 8) << 1);
        bb2 ^= (rb & 7) << 4;
        b[Nt] = *(const bfx8*)((const char*)Bs + bb2);
      }
#pragma unroll
      for (int Mt = 0; Mt < 4; ++Mt)
#pragma unroll
        for (int Nt = 0; Nt < 4; ++Nt)
          acc[Mt][Nt] = __builtin_amdgcn_mfma_f32_16x16x32_bf16(a[Mt], b[Nt], acc[Mt][Nt], 0, 0, 0);
    }
    __syncthreads();
  }
  float bv[4];
#pragma unroll
  for (int Nt = 0; Nt < 4; ++Nt) bv[Nt] = bias[n0 + noff + Nt * 16 + l15];
#pragma unroll
  for (int Mt = 0; Mt < 4; ++Mt)
#pragma unroll
    for (int Nt = 0; Nt < 4; ++Nt)
#pragma unroll
      for (int r = 0; r < 4; ++r) {
        int m = m0 + moff + Mt * 16 + l4 * 4 + r;
        int n = n0 + noff + Nt * 16 + l15;
        XP[((size_t)dir * M_ + m) * NG + n] = f2bf(acc[Mt][Nt][r] + bv[Nt]);
      }
}

// ---------------- R: persistent recurrent kernel ----------------
// 64 WGs = 2 dirs x 32 unit-slices. Per WG: rec weights (96 cols x 1024) in VGPRs,
// 4 waves split K (256 each), LDS partial reduce, fused gates.
// One device-scope barrier per timestep; h double-buffered bf16 in ws.
__global__ __launch_bounds__(256, 1) void k_gru(
    const u16* __restrict__ RW,    // [2][3072 packed rows][1024] bf16
    const u16* __restrict__ XP,    // [2][4096][3072] bf16
    const float* __restrict__ bf_, const float* __restrict__ bb_,
    u16* __restrict__ Hbuf,        // [2][2][32][1024] bf16
    float* __restrict__ out,       // y[32][128][1024] ++ hf[32][1024] ++ hb[32][1024]
    u32* __restrict__ bar) {
  const int tid = threadIdx.x;
  const int wave = tid >> 6, lane = tid & 63;
  const int wg = blockIdx.x;
  const int dir = wg & 1, slice = wg >> 1;
  const int u0 = slice * 32;
  const float* b1p = (dir ? bb_ : bf_) + NG;     // bias row 1 (recurrent)
  const u16* wbase = RW + (size_t)dir * NG * U_ + (size_t)slice * 96 * U_;
  const u16* xpd = XP + (size_t)dir * M_ * NG;
  u16* hb_d = Hbuf + (size_t)dir * 2 * B_ * U_;
  __shared__ float pl[4][32][96];                // 48KB: [wave][b][c] partials

  const int l15 = lane & 15, l4 = lane >> 4;
  const int kwave = wave * 256;

  // preload this wave's 48 weight frags (192 VGPRs) — resident for all 128 steps
  bfx8 wf[6][8];
#pragma unroll
  for (int Nt = 0; Nt < 6; ++Nt)
#pragma unroll
    for (int Ks = 0; Ks < 8; ++Ks) {
      int c = Nt * 16 + l15;
      int k = kwave + Ks * 32 + l4 * 8;
      wf[Nt][Ks] = *(const bfx8*)(wbase + (size_t)c * U_ + k);
    }

  const int ul = tid & 31, bg = tid >> 5;        // epilogue mapping: (b=bg*4+i, u=u0+ul)
  float b1[3];
#pragma unroll
  for (int g = 0; g < 3; ++g) b1[g] = b1p[g * U_ + u0 + ul];
  float hreg[4] = {0.f, 0.f, 0.f, 0.f};

  u32 target = 0;
  for (int e = 0; e < 128; ++e) {
    const int t = dir ? (127 - e) : e;
    // x_proj prefetch for this step (read-only data; independent of barrier)
    float xv[3][4];
#pragma unroll
    for (int i = 0; i < 4; ++i) {
      int b = bg * 4 + i;
      const u16* xr = xpd + (size_t)(t * 32 + b) * NG;
#pragma unroll
      for (int g = 0; g < 3; ++g) xv[g][i] = bf2f(xr[g * U_ + u0 + ul]);
    }
    f32x4 acc[2][6] = {};
    if (e > 0) {                                  // e==0: h=0 -> rec = bias1 only
      const u16* hsrc = hb_d + (size_t)(e & 1) * B_ * U_;
      bfx8 af[2][8];
#pragma unroll
      for (int Ks = 0; Ks < 8; ++Ks)
#pragma unroll
        for (int Mt = 0; Mt < 2; ++Mt) {
          int b = Mt * 16 + l15;
          int k = kwave + Ks * 32 + l4 * 8;
          af[Mt][Ks] = *(const bfx8*)(hsrc + (size_t)b * U_ + k);
        }
#pragma unroll
      for (int Ks = 0; Ks < 8; ++Ks)
#pragma unroll
        for (int Mt = 0; Mt < 2; ++Mt)
#pragma unroll
          for (int Nt = 0; Nt < 6; ++Nt)
            acc[Mt][Nt] = __builtin_amdgcn_mfma_f32_16x16x32_bf16(af[Mt][Ks], wf[Nt][Ks],
                                                                  acc[Mt][Nt], 0, 0, 0);
    }
    // dump partials: C/D layout col=lane&15, row=(lane>>4)*4+r
#pragma unroll
    for (int Mt = 0; Mt < 2; ++Mt)
#pragma unroll
      for (int Nt = 0; Nt < 6; ++Nt)
#pragma unroll
        for (int r = 0; r < 4; ++r)
          pl[wave][Mt * 16 + l4 * 4 + r][Nt * 16 + l15] = acc[Mt][Nt][r];
    __syncthreads();
    // reduce over 4 K-quarters + gates
#pragma unroll
    for (int i = 0; i < 4; ++i) {
      int b = bg * 4 + i;
      float red[3];
#pragma unroll
      for (int g = 0; g < 3; ++g) {
        int c = g * 32 + ul;
        red[g] = pl[0][b][c] + pl[1][b][c] + pl[2][b][c] + pl[3][b][c];
      }
      float z = sigm(xv[0][i] + red[0] + b1[0]);
      float r = sigm(xv[1][i] + red[1] + b1[1]);
      float hh = tanhf(xv[2][i] + r * (red[2] + b1[2]));
      float hn = z * hreg[i] + (1.f - z) * hh;
      hreg[i] = hn;
      hb_d[(size_t)(((e + 1) & 1) * B_ + b) * U_ + u0 + ul] = f2bf(hn);
      float* yp = out + ((size_t)b * T_ + t) * U_ + u0 + ul;
      if (e < 64) *yp = hn;     // first writer for this position
      else        *yp += hn;    // other dir wrote at epoch 127-t < e (fenced barriers between)
      if (e == 127) out[YN + (size_t)dir * (B_ * U_) + (size_t)b * U_ + u0 + ul] = hn;
    }
    if (e < 127) {
      __threadfence();          // push h (and y) to device-coherent point
      __syncthreads();
      target += 64;
      if (tid == 0) {
        __hip_atomic_fetch_add(bar, 1u, __ATOMIC_ACQ_REL, __HIP_MEMORY_SCOPE_AGENT);
        while (__hip_atomic_load(bar, __ATOMIC_ACQUIRE, __HIP_MEMORY_SCOPE_AGENT) < target)
          __builtin_amdgcn_s_sleep(2);
      }
      __syncthreads();
    }
  }
}

extern "C" void kernel_launch(void* const* d_in, const int* in_sizes, int n_in,
                              void* d_out, int out_size, void* d_ws, size_t ws_size,
                              hipStream_t stream) {
  const int*   tokens = (const int*)d_in[0];
  const float* emb    = (const float*)d_in[1];
  const float* kf     = (const float*)d_in[2];
  const float* rkf    = (const float*)d_in[3];
  const float* bf_    = (const float*)d_in[4];
  const float* kb     = (const float*)d_in[5];
  const float* rkb    = (const float*)d_in[6];
  const float* bb_    = (const float*)d_in[7];
  float* out = (float*)d_out;
  char* ws = (char*)d_ws;

  // workspace layout (bytes)
  u32* bar  = (u32*)ws;                               // 512
  u16* Hbuf = (u16*)(ws + 512);                       // 262144
  u16* X    = (u16*)(ws + 262656);                    // 4 MB
  u16* WT   = (u16*)(ws + 4456960);                   // 6 MB
  u16* RW   = (u16*)(ws + 10748416);                  // 12 MB
  u16* XP   = (u16*)(ws + 23331328);                  // 48 MB   (total ~70.3 MB)

  hipMemsetAsync(ws, 0, 512, stream);                 // reset barrier every call
  k_embed<<<1024, 256, 0, stream>>>(tokens, emb, X);
  k_transpose<<<dim3(16, 96), dim3(32, 8), 0, stream>>>(kf,  WT,                 512,  NG, 0);
  k_transpose<<<dim3(16, 96), dim3(32, 8), 0, stream>>>(kb,  WT + 3072 * 512,    512,  NG, 0);
  k_transpose<<<dim3(32, 96), dim3(32, 8), 0, stream>>>(rkf, RW,                 1024, NG, 1);
  k_transpose<<<dim3(32, 96), dim3(32, 8), 0, stream>>>(rkb, RW + 3072 * 1024,   1024, NG, 1);
  k_xproj<<<dim3(24, 32, 2), 256, 0, stream>>>(X, WT, bf_, bb_, XP);
  k_gru<<<64, 256, 0, stream>>>(RW, XP, bf_, bb_, Hbuf, out, bar);
}

// Round 2
// 827.508 us; speedup vs baseline: 2.0350x; 2.0350x over previous
//
#include <hip/hip_runtime.h>

// Bidirectional GRU (Keras reset_after) B=32,T=128,E=512,U=1024.
// embed-cast -> weight transposes -> x_proj GEMM -> persistent recurrent kernel
// with flag-based per-slice sync (sc0sc1 cache-bypass h exchange) -> y merge.

using u16 = unsigned short;
using u32 = unsigned int;
typedef __attribute__((ext_vector_type(8))) short bfx8;
typedef __attribute__((ext_vector_type(4))) float f32x4;

#define B_ 32
#define T_ 128
#define E_ 512
#define U_ 1024
#define NG 3072
#define M_ 4096
#define YN 4194304

__device__ __forceinline__ float bf2f(u16 u) {
  union { u32 i; float f; } v; v.i = (u32)u << 16; return v.f;
}
__device__ __forceinline__ u16 f2bf(float f) {
  union { float f; u32 i; } v; v.f = f;
  u32 r = v.i + 0x7FFFu + ((v.i >> 16) & 1u);
  return (u16)(r >> 16);
}
__device__ __forceinline__ float sigm(float x) { return 1.0f / (1.0f + __expf(-x)); }

__device__ __forceinline__ void load_lds16(const void* g, void* l) {
  __builtin_amdgcn_global_load_lds(
      (const __attribute__((address_space(1))) u32*)g,
      (__attribute__((address_space(3))) u32*)l, 16, 0, 0);
}

// ---------------- P1: embedding gather + cast ----------------
__global__ __launch_bounds__(256) void k_embed(const int* __restrict__ tok,
                                               const float* __restrict__ emb,
                                               u16* __restrict__ X) {
  int idx = blockIdx.x * 256 + threadIdx.x;
  int m = idx >> 6, k8 = (idx & 63) << 3;
  int b = m & 31, t = m >> 5;
  int tk = tok[b * T_ + t];
  const float* s = emb + (size_t)tk * E_ + k8;
  float4 v0 = *(const float4*)s, v1 = *(const float4*)(s + 4);
  bfx8 r;
  r[0]=(short)f2bf(v0.x); r[1]=(short)f2bf(v0.y); r[2]=(short)f2bf(v0.z); r[3]=(short)f2bf(v0.w);
  r[4]=(short)f2bf(v1.x); r[5]=(short)f2bf(v1.y); r[6]=(short)f2bf(v1.z); r[7]=(short)f2bf(v1.w);
  *(bfx8*)(X + (size_t)m * E_ + k8) = r;
}

// ---------------- P2: transpose/cast weights ----------------
__global__ void k_transpose(const float* __restrict__ in, u16* __restrict__ out,
                            int K, int N, int remap) {
  __shared__ float tile[32][33];
  int k0 = blockIdx.x * 32, n0 = blockIdx.y * 32;
  int tx = threadIdx.x, ty = threadIdx.y;
  for (int j = ty; j < 32; j += 8) tile[j][tx] = in[(size_t)(k0 + j) * N + n0 + tx];
  __syncthreads();
  for (int j = ty; j < 32; j += 8) {
    int n = n0 + j;
    int row = remap ? ((((n & 1023) >> 5) * 96) + ((n >> 10) << 5) + (n & 31)) : n;
    out[(size_t)row * K + k0 + tx] = f2bf(tile[tx][j]);
  }
}

// ---------------- G: x_proj GEMM ----------------
__global__ __launch_bounds__(256) void k_xproj(const u16* __restrict__ X,
                                               const u16* __restrict__ WT,
                                               const float* __restrict__ biasF,
                                               const float* __restrict__ biasB,
                                               u16* __restrict__ XP) {
  const int n0 = blockIdx.x * 128, m0 = blockIdx.y * 128, dir = blockIdx.z;
  const float* bias = dir ? biasB : biasF;
  const u16* Wd = WT + (size_t)dir * NG * E_;
  __shared__ __align__(16) u16 As[128 * 64];
  __shared__ __align__(16) u16 Bs[128 * 64];
  const int tid = threadIdx.x;
  const int wave = tid >> 6, lane = tid & 63;
  const int moff = (wave >> 1) * 64, noff = (wave & 1) * 64;
  const int l15 = lane & 15, l4 = lane >> 4;
  f32x4 acc[4][4] = {};
  for (int kt = 0; kt < 8; ++kt) {
    int k0 = kt * 64;
#pragma unroll
    for (int j = 0; j < 4; ++j) {
      int o = j * 4096 + tid * 16;
      int row = o >> 7;
      int kk = (((o & 127) ^ ((row & 7) << 4)) >> 1);
      load_lds16(X  + (size_t)(m0 + row) * E_ + k0 + kk, (char*)As + o);
      load_lds16(Wd + (size_t)(n0 + row) * E_ + k0 + kk, (char*)Bs + o);
    }
    __syncthreads();
#pragma unroll
    for (int Ks = 0; Ks < 2; ++Ks) {
      bfx8 a[4], b[4];
#pragma unroll
      for (int Mt = 0; Mt < 4; ++Mt) {
        int ra = moff + Mt * 16 + l15;
        int ba = (ra << 7) + ((Ks * 32 + l4 * 8) << 1);
        ba ^= (ra & 7) << 4;
        a[Mt] = *(const bfx8*)((const char*)As + ba);
      }
#pragma unroll
      for (int Nt = 0; Nt < 4; ++Nt) {
        int rb = noff + Nt * 16 + l15;
        int bb2 = (rb << 7) + ((Ks * 32 + l4 * 8) << 1);
        bb2 ^= (rb & 7) << 4;
        b[Nt] = *(const bfx8*)((const char*)Bs + bb2);
      }
#pragma unroll
      for (int Mt = 0; Mt < 4; ++Mt)
#pragma unroll
        for (int Nt = 0; Nt < 4; ++Nt)
          acc[Mt][Nt] = __builtin_amdgcn_mfma_f32_16x16x32_bf16(a[Mt], b[Nt], acc[Mt][Nt], 0, 0, 0);
    }
    __syncthreads();
  }
  float bv[4];
#pragma unroll
  for (int Nt = 0; Nt < 4; ++Nt) bv[Nt] = bias[n0 + noff + Nt * 16 + l15];
#pragma unroll
  for (int Mt = 0; Mt < 4; ++Mt)
#pragma unroll
    for (int Nt = 0; Nt < 4; ++Nt)
#pragma unroll
      for (int r = 0; r < 4; ++r) {
        int m = m0 + moff + Mt * 16 + l4 * 4 + r;
        int n = n0 + noff + Nt * 16 + l15;
        XP[((size_t)dir * M_ + m) * NG + n] = f2bf(acc[Mt][Nt][r] + bv[Nt]);
      }
}

// ---------------- R: persistent recurrent kernel ----------------
// 64 WGs = 2 dirs x 32 slices. Flag-array sync (no RMW, no fences):
//  - h stored/loaded via sc0 sc1 (IF-coherent, bypasses L1/L2)
//  - producer: drain vmcnt -> store flag[slice]=e+1 (sc0 sc1)
//  - consumer wave: spins on the 8 flags covering its K-range, target e
//  - y written one epoch late (h still in regs) into the dead 4KB head of
//    each consumed XP row (plain stores; ordering guaranteed by flag gates)
__global__ __launch_bounds__(256, 1) void k_gru(
    const u16* __restrict__ RW,
    u16* __restrict__ XP,
    const float* __restrict__ bf_, const float* __restrict__ bb_,
    u16* __restrict__ Hbuf,
    float* __restrict__ out,
    u32* __restrict__ flags) {
  const int tid = threadIdx.x;
  const int wave = tid >> 6, lane = tid & 63;
  const int wg = blockIdx.x;
  const int dir = wg & 1, slice = wg >> 1;
  const int u0 = slice * 32;
  const float* b1p = (dir ? bb_ : bf_) + NG;
  const u16* wbase = RW + (size_t)dir * NG * U_ + (size_t)slice * 96 * U_;
  u16* xpd = XP + (size_t)dir * M_ * NG;
  u16* hb_d = Hbuf + (size_t)dir * 2 * B_ * U_;
  u32* fl = flags + dir * 64;
  __shared__ float pl[4][32][96];

  const int l15 = lane & 15, l4 = lane >> 4;
  const int kwave = wave * 256;

  // preload this wave's 48 weight frags — resident all 128 steps
  bfx8 wf[6][8];
#pragma unroll
  for (int Nt = 0; Nt < 6; ++Nt)
#pragma unroll
    for (int Ks = 0; Ks < 8; ++Ks) {
      int c = Nt * 16 + l15;
      int k = kwave + Ks * 32 + l4 * 8;
      wf[Nt][Ks] = *(const bfx8*)(wbase + (size_t)c * U_ + k);
    }

  const int ul = tid & 31, bg = tid >> 5;
  float b1[3];
#pragma unroll
  for (int g = 0; g < 3; ++g) b1[g] = b1p[g * U_ + u0 + ul];
  float hreg[4] = {0.f, 0.f, 0.f, 0.f};

  const u32* myfl = fl + wave * 8 + (lane & 7);   // this wave's 8 producer flags
  u32* myflag = fl + slice;

  for (int e = 0; e < 128; ++e) {
    const int t = dir ? (127 - e) : e;
    // x_proj prefetch (plain cached loads; completes during gate spin)
    float xv[3][4];
#pragma unroll
    for (int i = 0; i < 4; ++i) {
      int b = bg * 4 + i;
      const u16* xr = xpd + (size_t)(t * 32 + b) * NG;
#pragma unroll
      for (int g = 0; g < 3; ++g) xv[g][i] = bf2f(xr[g * U_ + u0 + ul]);
    }
    f32x4 acc[2][6] = {};
    if (e > 0) {
      // gate: wait until our 8 K-range producers published h for step e
      while (1) {
        u32 v;
        asm volatile("global_load_dword %0, %1, off sc0 sc1\n\ts_waitcnt vmcnt(0)"
                     : "=&v"(v) : "v"(myfl) : "memory");
        if (__all((int)(v >= (u32)e))) break;
        __builtin_amdgcn_s_sleep(1);
      }
      // h fragment loads: IF-coherent bypass, issued back-to-back, one drain
      const u16* hsrc = hb_d + (size_t)(e & 1) * B_ * U_;
      bfx8 af[2][8];
#pragma unroll
      for (int Ks = 0; Ks < 8; ++Ks)
#pragma unroll
        for (int Mt = 0; Mt < 2; ++Mt) {
          const u16* hp = hsrc + (size_t)(Mt * 16 + l15) * U_ + kwave + Ks * 32 + l4 * 8;
          asm volatile("global_load_dwordx4 %0, %1, off sc0 sc1"
                       : "=&v"(af[Mt][Ks]) : "v"(hp));
        }
      asm volatile("s_waitcnt vmcnt(0)" ::: "memory");
      __builtin_amdgcn_sched_barrier(0);
#pragma unroll
      for (int Ks = 0; Ks < 8; ++Ks)
#pragma unroll
        for (int Mt = 0; Mt < 2; ++Mt)
#pragma unroll
          for (int Nt = 0; Nt < 6; ++Nt)
            acc[Mt][Nt] = __builtin_amdgcn_mfma_f32_16x16x32_bf16(af[Mt][Ks], wf[Nt][Ks],
                                                                  acc[Mt][Nt], 0, 0, 0);
    }
    // dump partials
#pragma unroll
    for (int Mt = 0; Mt < 2; ++Mt)
#pragma unroll
      for (int Nt = 0; Nt < 6; ++Nt)
#pragma unroll
        for (int r = 0; r < 4; ++r)
          pl[wave][Mt * 16 + l4 * 4 + r][Nt * 16 + l15] = acc[Mt][Nt][r];
    __syncthreads();
    // delayed y write for epoch e-1 (hreg not yet updated). Safe: all 32 flags
    // >= e here (union of the 4 waves' gates), so every WG of this dir has
    // drained its reads of XP row t_prev.
    if (e > 0) {
      const int tp = dir ? (128 - e) : (e - 1);
#pragma unroll
      for (int i = 0; i < 4; ++i) {
        int b = bg * 4 + i;
        float* yrow = (float*)(xpd + (size_t)(tp * 32 + b) * NG);
        yrow[u0 + ul] = hreg[i];
      }
    }
    // reduce K-quarters + gates
#pragma unroll
    for (int i = 0; i < 4; ++i) {
      int b = bg * 4 + i;
      float red[3];
#pragma unroll
      for (int g = 0; g < 3; ++g) {
        int c = g * 32 + ul;
        red[g] = pl[0][b][c] + pl[1][b][c] + pl[2][b][c] + pl[3][b][c];
      }
      float z = sigm(xv[0][i] + red[0] + b1[0]);
      float r = sigm(xv[1][i] + red[1] + b1[1]);
      float hh = tanhf(xv[2][i] + r * (red[2] + b1[2]));
      float hn = z * hreg[i] + (1.f - z) * hh;
      hreg[i] = hn;
      if (e < 127) {
        u16* hp = hb_d + (size_t)(((e + 1) & 1) * B_ + b) * U_ + u0 + ul;
        u32 hv = f2bf(hn);
        asm volatile("global_store_short %0, %1, off sc0 sc1"
                     :: "v"(hp), "v"(hv) : "memory");
      } else {
        out[YN + (size_t)dir * (B_ * U_) + (size_t)b * U_ + u0 + ul] = hn;
      }
    }
    asm volatile("s_waitcnt vmcnt(0)" ::: "memory");   // release: h (or out) drained
    __syncthreads();
    if (tid == 0) {
      u32 val = (u32)(e + 1);
      asm volatile("global_store_dword %0, %1, off sc0 sc1"
                   :: "v"(myflag), "v"(val) : "memory");
    }
  }
  // final: wait for all 32 slices to finish step 127, then write last y row
  {
    const u32* gf = fl + (lane & 31);
    while (1) {
      u32 v;
      asm volatile("global_load_dword %0, %1, off sc0 sc1\n\ts_waitcnt vmcnt(0)"
                   : "=&v"(v) : "v"(gf) : "memory");
      if (__all((int)(v >= 128u))) break;
      __builtin_amdgcn_s_sleep(1);
    }
    const int tl = dir ? 0 : 127;
#pragma unroll
    for (int i = 0; i < 4; ++i) {
      int b = bg * 4 + i;
      float* yrow = (float*)(xpd + (size_t)(tl * 32 + b) * NG);
      yrow[u0 + ul] = hreg[i];
    }
  }
}

// ---------------- M: y merge  out = yf + yb ----------------
__global__ __launch_bounds__(256) void k_merge(const u16* __restrict__ XP,
                                               float* __restrict__ out) {
  int idx = blockIdx.x * 256 + threadIdx.x;   // 1048576 threads
  int u4 = (idx & 255) * 4;
  int m = idx >> 8;                            // t*32+b
  int t = m >> 5, b = m & 31;
  const float* yf = (const float*)(XP + (size_t)m * NG);
  const float* yb = (const float*)(XP + (size_t)(M_ + m) * NG);
  float4 a = *(const float4*)(yf + u4);
  float4 c = *(const float4*)(yb + u4);
  float4 o; o.x = a.x + c.x; o.y = a.y + c.y; o.z = a.z + c.z; o.w = a.w + c.w;
  *(float4*)(out + ((size_t)b * T_ + t) * U_ + u4) = o;
}

extern "C" void kernel_launch(void* const* d_in, const int* in_sizes, int n_in,
                              void* d_out, int out_size, void* d_ws, size_t ws_size,
                              hipStream_t stream) {
  const int*   tokens = (const int*)d_in[0];
  const float* emb    = (const float*)d_in[1];
  const float* kf     = (const float*)d_in[2];
  const float* rkf    = (const float*)d_in[3];
  const float* bf_    = (const float*)d_in[4];
  const float* kb     = (const float*)d_in[5];
  const float* rkb    = (const float*)d_in[6];
  const float* bb_    = (const float*)d_in[7];
  float* out = (float*)d_out;
  char* ws = (char*)d_ws;

  u32* flags = (u32*)ws;                              // 512 B
  u16* Hbuf  = (u16*)(ws + 512);                      // 256 KB
  u16* X     = (u16*)(ws + 262656);                   // 4 MB
  u16* WT    = (u16*)(ws + 4456960);                  // 6 MB
  u16* RW    = (u16*)(ws + 10748416);                 // 12 MB
  u16* XP    = (u16*)(ws + 23331328);                 // 48 MB (y holes reuse this)

  hipMemsetAsync(ws, 0, 512, stream);                 // reset flags every call
  k_embed<<<1024, 256, 0, stream>>>(tokens, emb, X);
  k_transpose<<<dim3(16, 96), dim3(32, 8), 0, stream>>>(kf,  WT,               512,  NG, 0);
  k_transpose<<<dim3(16, 96), dim3(32, 8), 0, stream>>>(kb,  WT + 3072 * 512,  512,  NG, 0);
  k_transpose<<<dim3(32, 96), dim3(32, 8), 0, stream>>>(rkf, RW,               1024, NG, 1);
  k_transpose<<<dim3(32, 96), dim3(32, 8), 0, stream>>>(rkb, RW + 3072 * 1024, 1024, NG, 1);
  k_xproj<<<dim3(24, 32, 2), 256, 0, stream>>>(X, WT, bf_, bb_, XP);
  k_gru<<<64, 256, 0, stream>>>(RW, XP, bf_, bb_, Hbuf, out, flags);
  k_merge<<<4096, 256, 0, stream>>>(XP, out);
}

// Round 4
// 646.188 us; speedup vs baseline: 2.6061x; 1.2806x over previous
//
#include <hip/hip_runtime.h>

// Bidirectional GRU (Keras reset_after) B=32,T=128,E=512,U=1024.
// embed-cast -> weight transposes -> x_proj GEMM -> persistent recurrent kernel
// with SELF-VALIDATING epoch-tagged h exchange (no flags, no producer drains)
// -> y merge.

using u16 = unsigned short;
using u32 = unsigned int;
typedef __attribute__((ext_vector_type(8))) short bfx8;
typedef __attribute__((ext_vector_type(4))) float f32x4;
typedef __attribute__((ext_vector_type(4))) u32 u32x4;
typedef __attribute__((ext_vector_type(3))) u32 u32x3;
typedef __attribute__((ext_vector_type(4))) u16 u16x4;

#define B_ 32
#define T_ 128
#define E_ 512
#define U_ 1024
#define NG 3072
#define M_ 4096
#define YN 4194304
// Hx geometry: per dir, 3 rotating buffers; each [256 grp][32 b][16B]
// unit = {bf16 h[4k..4k+3] for row b (8B), u32 epoch tag, 4B pad}
#define ROTB 131072          // bytes per rotation buffer
#define HXD  393216          // bytes per dir (3 rotations)

__device__ __forceinline__ float bf2f(u16 u) {
  union { u32 i; float f; } v; v.i = (u32)u << 16; return v.f;
}
__device__ __forceinline__ u16 f2bf(float f) {
  union { float f; u32 i; } v; v.f = f;
  u32 r = v.i + 0x7FFFu + ((v.i >> 16) & 1u);
  return (u16)(r >> 16);
}
__device__ __forceinline__ float sigm(float x) { return 1.0f / (1.0f + __expf(-x)); }

__device__ __forceinline__ void load_lds16(const void* g, void* l) {
  __builtin_amdgcn_global_load_lds(
      (const __attribute__((address_space(1))) u32*)g,
      (__attribute__((address_space(3))) u32*)l, 16, 0, 0);
}

// ---------------- P1: embedding gather + cast ----------------
__global__ __launch_bounds__(256) void k_embed(const int* __restrict__ tok,
                                               const float* __restrict__ emb,
                                               u16* __restrict__ X) {
  int idx = blockIdx.x * 256 + threadIdx.x;
  int m = idx >> 6, k8 = (idx & 63) << 3;
  int b = m & 31, t = m >> 5;
  int tk = tok[b * T_ + t];
  const float* s = emb + (size_t)tk * E_ + k8;
  float4 v0 = *(const float4*)s, v1 = *(const float4*)(s + 4);
  bfx8 r;
  r[0]=(short)f2bf(v0.x); r[1]=(short)f2bf(v0.y); r[2]=(short)f2bf(v0.z); r[3]=(short)f2bf(v0.w);
  r[4]=(short)f2bf(v1.x); r[5]=(short)f2bf(v1.y); r[6]=(short)f2bf(v1.z); r[7]=(short)f2bf(v1.w);
  *(bfx8*)(X + (size_t)m * E_ + k8) = r;
}

// ---------------- P2: transpose/cast weights ----------------
__global__ void k_transpose(const float* __restrict__ in, u16* __restrict__ out,
                            int K, int N, int remap) {
  __shared__ float tile[32][33];
  int k0 = blockIdx.x * 32, n0 = blockIdx.y * 32;
  int tx = threadIdx.x, ty = threadIdx.y;
  for (int j = ty; j < 32; j += 8) tile[j][tx] = in[(size_t)(k0 + j) * N + n0 + tx];
  __syncthreads();
  for (int j = ty; j < 32; j += 8) {
    int n = n0 + j;
    int row = remap ? ((((n & 1023) >> 5) * 96) + ((n >> 10) << 5) + (n & 31)) : n;
    out[(size_t)row * K + k0 + tx] = f2bf(tile[tx][j]);
  }
}

// ---------------- G: x_proj GEMM ----------------
__global__ __launch_bounds__(256) void k_xproj(const u16* __restrict__ X,
                                               const u16* __restrict__ WT,
                                               const float* __restrict__ biasF,
                                               const float* __restrict__ biasB,
                                               u16* __restrict__ XP) {
  const int n0 = blockIdx.x * 128, m0 = blockIdx.y * 128, dir = blockIdx.z;
  const float* bias = dir ? biasB : biasF;
  const u16* Wd = WT + (size_t)dir * NG * E_;
  __shared__ __align__(16) u16 As[128 * 64];
  __shared__ __align__(16) u16 Bs[128 * 64];
  const int tid = threadIdx.x;
  const int wave = tid >> 6, lane = tid & 63;
  const int moff = (wave >> 1) * 64, noff = (wave & 1) * 64;
  const int l15 = lane & 15, l4 = lane >> 4;
  f32x4 acc[4][4] = {};
  for (int kt = 0; kt < 8; ++kt) {
    int k0 = kt * 64;
#pragma unroll
    for (int j = 0; j < 4; ++j) {
      int o = j * 4096 + tid * 16;
      int row = o >> 7;
      int kk = (((o & 127) ^ ((row & 7) << 4)) >> 1);
      load_lds16(X  + (size_t)(m0 + row) * E_ + k0 + kk, (char*)As + o);
      load_lds16(Wd + (size_t)(n0 + row) * E_ + k0 + kk, (char*)Bs + o);
    }
    __syncthreads();
#pragma unroll
    for (int Ks = 0; Ks < 2; ++Ks) {
      bfx8 a[4], b[4];
#pragma unroll
      for (int Mt = 0; Mt < 4; ++Mt) {
        int ra = moff + Mt * 16 + l15;
        int ba = (ra << 7) + ((Ks * 32 + l4 * 8) << 1);
        ba ^= (ra & 7) << 4;
        a[Mt] = *(const bfx8*)((const char*)As + ba);
      }
#pragma unroll
      for (int Nt = 0; Nt < 4; ++Nt) {
        int rb = noff + Nt * 16 + l15;
        int bb2 = (rb << 7) + ((Ks * 32 + l4 * 8) << 1);
        bb2 ^= (rb & 7) << 4;
        b[Nt] = *(const bfx8*)((const char*)Bs + bb2);
      }
#pragma unroll
      for (int Mt = 0; Mt < 4; ++Mt)
#pragma unroll
        for (int Nt = 0; Nt < 4; ++Nt)
          acc[Mt][Nt] = __builtin_amdgcn_mfma_f32_16x16x32_bf16(a[Mt], b[Nt], acc[Mt][Nt], 0, 0, 0);
    }
    __syncthreads();
  }
  float bv[4];
#pragma unroll
  for (int Nt = 0; Nt < 4; ++Nt) bv[Nt] = bias[n0 + noff + Nt * 16 + l15];
#pragma unroll
  for (int Mt = 0; Mt < 4; ++Mt)
#pragma unroll
    for (int Nt = 0; Nt < 4; ++Nt)
#pragma unroll
      for (int r = 0; r < 4; ++r) {
        int m = m0 + moff + Mt * 16 + l4 * 4 + r;
        int n = n0 + noff + Nt * 16 + l15;
        XP[((size_t)dir * M_ + m) * NG + n] = f2bf(acc[Mt][Nt][r] + bv[Nt]);
      }
}

// ---------------- R: persistent recurrent kernel ----------------
// 64 WGs = 2 dirs x 32 slices. h exchange via epoch-tagged 12B-in-16B units:
// a load returning tag==e atomically carries step-e data -> the load IS the
// gate. 3-buffer rotation makes overwrites race-free. No producer drains, no
// flags. y written one epoch late into dead XP row heads.
__global__ __launch_bounds__(256, 1) void k_gru(
    const u16* __restrict__ RW,
    u16* __restrict__ XP,
    const float* __restrict__ bf_, const float* __restrict__ bb_,
    char* __restrict__ Hx,
    float* __restrict__ out) {
  const int tid = threadIdx.x;
  const int wave = tid >> 6, lane = tid & 63;
  const int wg = blockIdx.x;
  const int dir = wg & 1, slice = wg >> 1;
  const int u0 = slice * 32;
  const float* b1p = (dir ? bb_ : bf_) + NG;
  const u16* wbase = RW + (size_t)dir * NG * U_ + (size_t)slice * 96 * U_;
  u16* xpd = XP + (size_t)dir * M_ * NG;
  char* hxd = Hx + (size_t)dir * HXD;
  __shared__ float pl[4][32][97];                 // stride 97: bank spread

  const int l15 = lane & 15, l4 = lane >> 4;

  // preload this wave's 48 weight frags — resident all 128 steps
  bfx8 wf[6][8];
#pragma unroll
  for (int Nt = 0; Nt < 6; ++Nt)
#pragma unroll
    for (int Ks = 0; Ks < 8; ++Ks) {
      int c = Nt * 16 + l15;
      int k = wave * 256 + Ks * 32 + l4 * 8;
      wf[Nt][Ks] = *(const bfx8*)(wbase + (size_t)c * U_ + k);
    }

  // epilogue mapping: thread owns (b=eb, units u0+uu..u0+uu+3)
  const int eb = tid & 31;
  const int ug = tid >> 5;
  const int uu = ug * 4;
  float b1[3][4];
#pragma unroll
  for (int g = 0; g < 3; ++g)
#pragma unroll
    for (int j = 0; j < 4; ++j) b1[g][j] = b1p[g * U_ + u0 + uu + j];
  float hreg[4] = {0.f, 0.f, 0.f, 0.f};

  // consumer per-lane byte offset within a rotation buffer
  const int offb = wave * 32768 + l4 * 1024 + l15 * 16;
  // probe: one tag per producer slice in this wave's K-range
  const int sp = wave * 8 + (lane & 7);
  const int poff = (8 * sp + 7) * 512 + 31 * 16 + 8;
  // producer store offset (within rotation)
  const int soff = (slice * 8 + ug) * 512 + eb * 16;

  int rl = 0, rs = 1;                              // rl = e%3, rs = (e+1)%3
  for (int e = 0; e < 128; ++e) {
    const int t = dir ? (127 - e) : e;
    // x_proj loads (plain cached; drain overlaps with first probe)
    float xvf[3][4];
    {
      const u16* xr = xpd + (size_t)(t * 32 + eb) * NG + u0 + uu;
#pragma unroll
      for (int g = 0; g < 3; ++g) {
        u16x4 w = *(const u16x4*)(xr + g * U_);
#pragma unroll
        for (int j = 0; j < 4; ++j) xvf[g][j] = bf2f(w[j]);
      }
    }
    f32x4 acc[2][6] = {};
    if (e > 0) {
      const u32 etag = (u32)e;
      char* rbase = hxd + rl * ROTB;
      // -- probe poll (cheap): one tag per slice in this wave's K-range
      {
        const char* pa = rbase + poff;
        u32 tv = etag;
        while (1) {
          if (lane < 8) {
            asm volatile("global_load_dword %0, %1, off sc0 sc1\n\ts_waitcnt vmcnt(0)"
                         : "=v"(tv) : "v"(pa));
          }
          if (__all((int)(tv == etag))) break;
          __builtin_amdgcn_s_sleep(1);
        }
      }
      // -- bulk self-validating load of all 16 h fragments
      u32x3 L[2][8][2];
      while (1) {
#pragma unroll
        for (int Ks = 0; Ks < 8; ++Ks) {
          const char* a = rbase + offb + Ks * 4096;
          asm volatile("global_load_dwordx3 %0, %1, off sc0 sc1"             : "=v"(L[0][Ks][0]) : "v"(a));
          asm volatile("global_load_dwordx3 %0, %1, off offset:512 sc0 sc1" : "=v"(L[0][Ks][1]) : "v"(a));
          asm volatile("global_load_dwordx3 %0, %1, off offset:256 sc0 sc1" : "=v"(L[1][Ks][0]) : "v"(a));
          asm volatile("global_load_dwordx3 %0, %1, off offset:768 sc0 sc1" : "=v"(L[1][Ks][1]) : "v"(a));
        }
        asm volatile("s_waitcnt vmcnt(0)");
#pragma unroll
        for (int Mt = 0; Mt < 2; ++Mt)
#pragma unroll
          for (int Ks = 0; Ks < 8; ++Ks)
            asm volatile("" : "+v"(L[Mt][Ks][0]), "+v"(L[Mt][Ks][1]));
        u32 bad = 0;
#pragma unroll
        for (int Mt = 0; Mt < 2; ++Mt)
#pragma unroll
          for (int Ks = 0; Ks < 8; ++Ks)
            bad |= (L[Mt][Ks][0].z ^ etag) | (L[Mt][Ks][1].z ^ etag);
        if (__all((int)(bad == 0))) break;
        __builtin_amdgcn_s_sleep(1);
      }
      // -- extract fragments and run MFMA
      bfx8 af[2][8];
#pragma unroll
      for (int Mt = 0; Mt < 2; ++Mt)
#pragma unroll
        for (int Ks = 0; Ks < 8; ++Ks) {
          u32x4 fv = {L[Mt][Ks][0].x, L[Mt][Ks][0].y, L[Mt][Ks][1].x, L[Mt][Ks][1].y};
          af[Mt][Ks] = __builtin_bit_cast(bfx8, fv);
        }
      __builtin_amdgcn_sched_barrier(0);
#pragma unroll
      for (int Ks = 0; Ks < 8; ++Ks)
#pragma unroll
        for (int Mt = 0; Mt < 2; ++Mt)
#pragma unroll
          for (int Nt = 0; Nt < 6; ++Nt)
            acc[Mt][Nt] = __builtin_amdgcn_mfma_f32_16x16x32_bf16(af[Mt][Ks], wf[Nt][Ks],
                                                                  acc[Mt][Nt], 0, 0, 0);
    }
    // dump partials: C/D layout col=lane&15, row=(lane>>4)*4+r
#pragma unroll
    for (int Mt = 0; Mt < 2; ++Mt)
#pragma unroll
      for (int Nt = 0; Nt < 6; ++Nt)
#pragma unroll
        for (int r = 0; r < 4; ++r)
          pl[wave][Mt * 16 + l4 * 4 + r][Nt * 16 + l15] = acc[Mt][Nt][r];
    __syncthreads();
    // deferred y for epoch e-1 (pre-update hreg). Safe: the 4 waves' gates
    // union over all 32 slices => every WG finished its epoch-(e-1) XP reads.
    if (e > 0) {
      const int tp = dir ? (128 - e) : (e - 1);
      float* yrow = (float*)(xpd + (size_t)(tp * 32 + eb) * NG);
      *(float4*)(yrow + u0 + uu) = make_float4(hreg[0], hreg[1], hreg[2], hreg[3]);
    }
    // reduce K-quarters + gates
#pragma unroll
    for (int j = 0; j < 4; ++j) {
      int c = uu + j;
      float rz = pl[0][eb][c]      + pl[1][eb][c]      + pl[2][eb][c]      + pl[3][eb][c];
      float rr = pl[0][eb][32 + c] + pl[1][eb][32 + c] + pl[2][eb][32 + c] + pl[3][eb][32 + c];
      float rh = pl[0][eb][64 + c] + pl[1][eb][64 + c] + pl[2][eb][64 + c] + pl[3][eb][64 + c];
      float z  = sigm(xvf[0][j] + rz + b1[0][j]);
      float r  = sigm(xvf[1][j] + rr + b1[1][j]);
      float hh = tanhf(xvf[2][j] + r * (rh + b1[2][j]));
      hreg[j] = z * hreg[j] + (1.f - z) * hh;
    }
    // publish h+tag (single 12B atomic store; no drain needed)
    {
      u32 p01 = (u32)f2bf(hreg[0]) | ((u32)f2bf(hreg[1]) << 16);
      u32 p23 = (u32)f2bf(hreg[2]) | ((u32)f2bf(hreg[3]) << 16);
      u32x3 sv; sv.x = p01; sv.y = p23; sv.z = (u32)(e + 1);
      char* sa = hxd + rs * ROTB + soff;
      asm volatile("global_store_dwordx3 %0, %1, off sc0 sc1" :: "v"(sa), "v"(sv));
    }
    rl = rs; rs = (rs == 2) ? 0 : rs + 1;
    __syncthreads();          // protect pl against next epoch's dump
  }
  // final: wait for all 32 slices' tag-128 (rot 2), then last y row + states
  {
    const char* pa = hxd + 2 * ROTB + (8 * (lane & 31) + 7) * 512 + 31 * 16 + 8;
    u32 tv = 128u;
    while (1) {
      if (lane < 32) {
        asm volatile("global_load_dword %0, %1, off sc0 sc1\n\ts_waitcnt vmcnt(0)"
                     : "=v"(tv) : "v"(pa));
      }
      if (__all((int)(tv == 128u))) break;
      __builtin_amdgcn_s_sleep(1);
    }
    const int tl = dir ? 0 : 127;
    float* yrow = (float*)(xpd + (size_t)(tl * 32 + eb) * NG);
    *(float4*)(yrow + u0 + uu) = make_float4(hreg[0], hreg[1], hreg[2], hreg[3]);
    float* os = out + YN + (size_t)dir * (B_ * U_) + (size_t)eb * U_ + u0 + uu;
    *(float4*)os = make_float4(hreg[0], hreg[1], hreg[2], hreg[3]);
  }
}

// ---------------- M: y merge  out = yf + yb ----------------
__global__ __launch_bounds__(256) void k_merge(const u16* __restrict__ XP,
                                               float* __restrict__ out) {
  int idx = blockIdx.x * 256 + threadIdx.x;
  int u4 = (idx & 255) * 4;
  int m = idx >> 8;                            // t*32+b
  int t = m >> 5, b = m & 31;
  const float* yf = (const float*)(XP + (size_t)m * NG);
  const float* yb = (const float*)(XP + (size_t)(M_ + m) * NG);
  float4 a = *(const float4*)(yf + u4);
  float4 c = *(const float4*)(yb + u4);
  float4 o; o.x = a.x + c.x; o.y = a.y + c.y; o.z = a.z + c.z; o.w = a.w + c.w;
  *(float4*)(out + ((size_t)b * T_ + t) * U_ + u4) = o;
}

extern "C" void kernel_launch(void* const* d_in, const int* in_sizes, int n_in,
                              void* d_out, int out_size, void* d_ws, size_t ws_size,
                              hipStream_t stream) {
  const int*   tokens = (const int*)d_in[0];
  const float* emb    = (const float*)d_in[1];
  const float* kf     = (const float*)d_in[2];
  const float* rkf    = (const float*)d_in[3];
  const float* bf_    = (const float*)d_in[4];
  const float* kb     = (const float*)d_in[5];
  const float* rkb    = (const float*)d_in[6];
  const float* bb_    = (const float*)d_in[7];
  float* out = (float*)d_out;
  char* ws = (char*)d_ws;

  // workspace layout. Hx ALIASES WT (WT dead after k_xproj; memset is
  // stream-ordered after k_xproj, before k_gru).
  u16*  X  = (u16*)ws;                        // 4 MB
  u16*  WT = (u16*)(ws + 0x400000);           // 6 MB
  char* Hx = ws + 0x400000;                   // 768 KB (aliases WT)
  u16*  RW = (u16*)(ws + 0xA00000);           // 12 MB
  u16*  XP = (u16*)(ws + 0x1600000);          // 48 MB (y stashed in row heads)

  k_embed<<<1024, 256, 0, stream>>>(tokens, emb, X);
  k_transpose<<<dim3(16, 96), dim3(32, 8), 0, stream>>>(kf,  WT,               512,  NG, 0);
  k_transpose<<<dim3(16, 96), dim3(32, 8), 0, stream>>>(kb,  WT + 3072 * 512,  512,  NG, 0);
  k_transpose<<<dim3(32, 96), dim3(32, 8), 0, stream>>>(rkf, RW,               1024, NG, 1);
  k_transpose<<<dim3(32, 96), dim3(32, 8), 0, stream>>>(rkb, RW + 3072 * 1024, 1024, NG, 1);
  k_xproj<<<dim3(24, 32, 2), 256, 0, stream>>>(X, WT, bf_, bb_, XP);
  hipMemsetAsync(Hx, 0, 2 * HXD, stream);     // clear epoch tags (also per replay)
  k_gru<<<64, 256, 0, stream>>>(RW, XP, bf_, bb_, Hx, out);
  k_merge<<<4096, 256, 0, stream>>>(XP, out);
}